// Round 14
// baseline (2105.362 us; speedup 1.0000x reference)
//
#include <hip/hip_runtime.h>
#include <stdint.h>

#define NTOK 9600
#define TT   300
#define DD   1024
#define HH   8
#define DFF  4096
#define FIN  1152
#define DATT 128
#define NCLS 3862
#define TP   320   // kv padded for PV k-steps
#define NQT  19    // ceil(304/16) tiles of 16

typedef unsigned short u16;
typedef __attribute__((ext_vector_type(8))) short short8;
typedef __attribute__((ext_vector_type(4))) float f32x4;

__device__ __forceinline__ int imin(int a, int b){ return a < b ? a : b; }

__device__ __forceinline__ u16 f2bf(float f){
    union { float f; uint32_t u; } v; v.f = f;
    uint32_t u = v.u;
    return (u16)((u + 0x7fffu + ((u >> 16) & 1u)) >> 16);
}

__device__ __forceinline__ f32x4 mfma16(short8 a, short8 b, f32x4 c){
    return __builtin_amdgcn_mfma_f32_16x16x32_bf16(a, b, c, 0, 0, 0);
}

// async global->LDS, 16B per lane. LDS dest must be wave-uniform base + lane*16 (linear).
__device__ __forceinline__ void gll16(const void* g, void* l){
    __builtin_amdgcn_global_load_lds((const __attribute__((address_space(1))) void*)g,
                                     (__attribute__((address_space(3))) void*)l, 16, 0, 0);
}

// ---------------- PE table ----------------
__global__ void __launch_bounds__(256) pe_kernel(float* __restrict__ pe)
{
    const int i = blockIdx.x * 256 + threadIdx.x;
    if (i >= TT * DD) return;
    const int t = i >> 10, d = i & 1023;
    const float fr = expf(-(float)(d & ~1) * (9.210340371976184f / 1024.0f));
    const float ang = (float)t * fr;
    pe[i] = (d & 1) ? cosf(ang) : sinf(ang);
}

// ---------------- feats concat + /255 -> bf16 ----------------
__global__ void __launch_bounds__(256) feats_kernel(const float* __restrict__ rgb,
        const float* __restrict__ aud, u16* __restrict__ out)
{
    const long i = (long)blockIdx.x * 256 + threadIdx.x;
    if (i >= (long)NTOK * FIN) return;
    const int row = (int)(i / FIN), c = (int)(i % FIN);
    const float v = (c < 1024) ? rgb[(size_t)row * 1024 + c] : aud[(size_t)row * 128 + (c - 1024)];
    out[i] = f2bf(v * (1.0f / 255.0f));
}

// ---------------- weight transpose + convert: W[K,N] f32 -> Wt[N,K] bf16 ----------------
__global__ void __launch_bounds__(256) wconv_kernel(const float* __restrict__ W,
        u16* __restrict__ Wt, int K, int N)
{
    __shared__ float tile[32][33];
    const int k0 = blockIdx.y * 32, n0 = blockIdx.x * 32;
    const int tx = threadIdx.x, ty = threadIdx.y;   // 32 x 8
    #pragma unroll
    for (int i = 0; i < 4; ++i) {
        const int k = k0 + ty + i * 8, n = n0 + tx;
        tile[ty + i * 8][tx] = (k < K && n < N) ? W[(size_t)k * N + n] : 0.f;
    }
    __syncthreads();
    #pragma unroll
    for (int i = 0; i < 4; ++i) {
        const int n = n0 + ty + i * 8, k = k0 + tx;
        if (n < N && k < K) Wt[(size_t)n * K + k] = f2bf(tile[tx][ty + i * 8]);
    }
}

// ---------------- batched x3 (QKV) weight transpose: 1024x1024 each ----------------
__global__ void __launch_bounds__(256) wconv3_kernel(const float* __restrict__ W0,
        const float* __restrict__ W1, const float* __restrict__ W2, u16* __restrict__ Wt)
{
    __shared__ float tile[32][33];
    const float* W = (blockIdx.z == 0) ? W0 : ((blockIdx.z == 1) ? W1 : W2);
    u16* dst = Wt + (size_t)blockIdx.z * DD * DD;
    const int k0 = blockIdx.y * 32, n0 = blockIdx.x * 32;
    const int tx = threadIdx.x, ty = threadIdx.y;   // 32 x 8
    #pragma unroll
    for (int i = 0; i < 4; ++i)
        tile[ty + i * 8][tx] = W[(size_t)(k0 + ty + i * 8) * DD + n0 + tx];
    __syncthreads();
    #pragma unroll
    for (int i = 0; i < 4; ++i)
        dst[(size_t)(n0 + ty + i * 8) * DD + k0 + tx] = f2bf(tile[tx][ty + i * 8]);
}

// ---------------- f32 -> bf16 ----------------
__global__ void __launch_bounds__(256) f2bf_kernel(const float* __restrict__ in,
        u16* __restrict__ out, int n)
{
    const int i = blockIdx.x * 256 + threadIdx.x;
    if (i < n) out[i] = f2bf(in[i]);
}

// ---------------- fused QKV bias gather: [4][3072] ----------------
__global__ void __launch_bounds__(256) qkvbias_kernel(const float* __restrict__ bq,
        const float* __restrict__ bk, const float* __restrict__ bv, float* __restrict__ out)
{
    const int i = blockIdx.x * 256 + threadIdx.x;
    if (i >= 4 * 3072) return;
    const int l = i / 3072, c = i % 3072;
    float v;
    if      (c < 1024) v = bq[l * 1024 + c];
    else if (c < 2048) v = bk[l * 1024 + c - 1024];
    else               v = bv[l * 1024 + c - 2048];
    out[i] = v;
}

// ---------------- LayerNorm (ddof=1, a*(x-m)/(std+eps)+b) ----------------
template<int WF>
__global__ void __launch_bounds__(256) ln_kernel(const float* __restrict__ xin,
        const float* __restrict__ ga, const float* __restrict__ gb,
        u16* __restrict__ ob, float* of)
{
    const int row = blockIdx.x, t = threadIdx.x;
    const float4 xv = *(const float4*)(xin + (size_t)row * 1024 + t * 4);
    float s1 = xv.x + xv.y + xv.z + xv.w;
    float s2 = xv.x * xv.x + xv.y * xv.y + xv.z * xv.z + xv.w * xv.w;
    #pragma unroll
    for (int o = 1; o < 64; o <<= 1) { s1 += __shfl_xor(s1, o); s2 += __shfl_xor(s2, o); }
    __shared__ float r1[4], r2[4];
    const int lane = t & 63, wid = t >> 6;
    if (lane == 0) { r1[wid] = s1; r2[wid] = s2; }
    __syncthreads();
    s1 = r1[0] + r1[1] + r1[2] + r1[3];
    s2 = r2[0] + r2[1] + r2[2] + r2[3];
    const float mean = s1 * (1.0f / 1024.0f);
    const float var  = (s2 - 1024.0f * mean * mean) * (1.0f / 1023.0f);
    const float inv  = 1.0f / (sqrtf(fmaxf(var, 0.f)) + 1e-6f);
    const float4 av  = *(const float4*)(ga + t * 4);
    const float4 bv  = *(const float4*)(gb + t * 4);
    const float y0 = av.x * (xv.x - mean) * inv + bv.x;
    const float y1 = av.y * (xv.y - mean) * inv + bv.y;
    const float y2 = av.z * (xv.z - mean) * inv + bv.z;
    const float y3 = av.w * (xv.w - mean) * inv + bv.w;
    ushort4 o4; o4.x = f2bf(y0); o4.y = f2bf(y1); o4.z = f2bf(y2); o4.w = f2bf(y3);
    *(ushort4*)(ob + (size_t)row * 1024 + t * 4) = o4;
    if (WF) {
        float4 yo; yo.x = y0; yo.y = y1; yo.z = y2; yo.w = y3;
        *(float4*)(of + (size_t)row * 1024 + t * 4) = yo;
    }
}

// ---------------- epilogue codes ----------------
#define EPI_EMBED        0
#define EPI_QKV          1   // route col>>10 to outB/outB2/outB3 (stride 1024)
#define EPI_B_RELU_BF16  2
#define EPI_B_RES_F32    3
#define EPI_B_TANH_F32   4
#define EPI_ACC_F32      5   // outF = v + extra (no bias; FFN2 second half)
#define EPI_PART         6   // partials for split-K: outF[z*M*N + oi] = v

// ---- generic bf16 MFMA GEMM: C = A[M,K] * Bt[N,K]^T (128x128, 2-phase dbuf; classifier) ----
template<int EPI, int SWZ>
__global__ void __launch_bounds__(256) gemm_k(const u16* __restrict__ A, const u16* __restrict__ Bt,
        const float* __restrict__ bias, const float* extra,
        float* outF, u16* outB, u16* outB2, u16* outB3, int M, int N, int K,
        int lda, int ldb, int kchunk)
{
    __shared__ __align__(16) u16 As[2][4096];
    __shared__ __align__(16) u16 Bs[2][4096];
    const int tid = threadIdx.x;
    int bm, bn;
    if (SWZ) {
        int lin = blockIdx.y * gridDim.x + blockIdx.x;
        const int nwg = gridDim.x * gridDim.y;
        const int cpx = nwg >> 3;
        lin = (lin & 7) * cpx + (lin >> 3);
        bm = lin / gridDim.x;
        bn = lin - bm * gridDim.x;
    } else {
        bm = blockIdx.y; bn = blockIdx.x;
    }
    const int lane = tid & 63, wid = tid >> 6;
    const int lg = lane >> 4, lr = lane & 15;
    const int wr = wid >> 1, wc = wid & 1;

    int koff = 0, Keff = K;
    if (kchunk > 0) { koff = blockIdx.z * kchunk; Keff = kchunk; }

    const int srow = tid >> 2;
    const int skc  = (tid & 3) * 8;
    const u16* ap0 = A  + (size_t)imin(bm * 128 + srow,      M - 1) * lda + skc + koff;
    const u16* ap1 = A  + (size_t)imin(bm * 128 + srow + 64, M - 1) * lda + skc + koff;
    const u16* bp0 = Bt + (size_t)imin(bn * 128 + srow,      N - 1) * ldb + skc + koff;
    const u16* bp1 = Bt + (size_t)imin(bn * 128 + srow + 64, N - 1) * ldb + skc + koff;

    f32x4 acc[4][4] = {};

    auto STAGE = [&](int b, int k0) {
        gll16(ap0 + k0, &As[b][tid * 8]);
        gll16(ap1 + k0, &As[b][2048 + tid * 8]);
        gll16(bp0 + k0, &Bs[b][tid * 8]);
        gll16(bp1 + k0, &Bs[b][2048 + tid * 8]);
    };
    auto COMPUTE = [&](int b) {
        short8 af[4], bf[4];
        #pragma unroll
        for (int m = 0; m < 4; ++m)
            af[m] = *(const short8*)(&As[b][(wr * 64 + m * 16 + lr) * 32 + lg * 8]);
        #pragma unroll
        for (int n = 0; n < 4; ++n)
            bf[n] = *(const short8*)(&Bs[b][(wc * 64 + n * 16 + lr) * 32 + lg * 8]);
        #pragma unroll
        for (int m = 0; m < 4; ++m)
            #pragma unroll
            for (int n = 0; n < 4; ++n)
                acc[m][n] = mfma16(af[m], bf[n], acc[m][n]);
    };

    STAGE(0, 0);
    __syncthreads();
    int cur = 0;
    for (int k0 = 32; k0 < Keff; k0 += 32) {
        STAGE(cur ^ 1, k0);
        COMPUTE(cur);
        __syncthreads();
        cur ^= 1;
    }
    COMPUTE(cur);

    #pragma unroll
    for (int m = 0; m < 4; ++m) {
        const int rb = bm * 128 + wr * 64 + m * 16 + lg * 4;
        #pragma unroll
        for (int n = 0; n < 4; ++n) {
            const int col = bn * 128 + wc * 64 + n * 16 + lr;
            if (col >= N) continue;
            const float bvl = (EPI == EPI_PART || EPI == EPI_ACC_F32) ? 0.f : bias[col];
            #pragma unroll
            for (int j = 0; j < 4; ++j) {
                const int r = rb + j;
                if (r >= M) continue;
                const float v = acc[m][n][j];
                const size_t oi = (size_t)r * N + col;
                if      (EPI == EPI_EMBED)       outF[oi] = (v + bvl) * 32.0f + extra[(size_t)(r % 300) * 1024 + col];
                else if (EPI == EPI_QKV) {
                    const int q = col >> 10, lc = col & 1023;
                    u16* dst = (q == 0) ? outB : ((q == 1) ? outB2 : outB3);
                    dst[(size_t)r * 1024 + lc] = f2bf(v + bvl);
                }
                else if (EPI == EPI_B_RELU_BF16) outB[oi] = f2bf(fmaxf(v + bvl, 0.f));
                else if (EPI == EPI_B_RES_F32)   outF[oi] = v + bvl + extra[oi];
                else if (EPI == EPI_B_TANH_F32)  outF[oi] = tanhf(v + bvl);
                else if (EPI == EPI_ACC_F32)     outF[oi] = v + extra[oi];
                else if (EPI == EPI_PART)        outF[(size_t)blockIdx.z * M * N + oi] = v;
            }
        }
    }
}

// ==== 256x256 BK=32 ring-2 counted-vmcnt GEMM, 512 threads (small-ws fallback only) ====
template<int EPI>
__global__ void __launch_bounds__(512, 2) gemm_big(const u16* __restrict__ A, const u16* __restrict__ Bt,
        const float* __restrict__ bias, const float* __restrict__ extra,
        float* outF, u16* outB, u16* outB2, u16* outB3,
        int M, int N, int K, int lda, int ldb, int kchunk)
{
    __shared__ __align__(16) u16 LA[2][256 * 32];
    __shared__ __align__(16) u16 LB[2][256 * 32];
    const int tid = threadIdx.x;
    int lin = blockIdx.x;
    const int nwg = gridDim.x;
    if ((nwg & 7) == 0) { const int cpx = nwg >> 3; lin = (lin & 7) * cpx + (lin >> 3); }
    int z = 0;
    if (kchunk > 0) { z = lin & 1; lin >>= 1; }
    const int ntN = N >> 8;
    const int bm = lin / ntN, bn = lin - (lin / ntN) * ntN;
    const int koff = z * kchunk;
    const int Keff = (kchunk > 0) ? kchunk : K;

    const int lane = tid & 63, wid = tid >> 6;
    const int wm = wid >> 2, wn = wid & 3;
    const int lg = lane >> 4, lr = lane & 15;

    const int prow = tid >> 2;
    const int skg  = (((tid & 3) ^ ((tid >> 3) & 3)) * 8);
    const u16* asrc0 = A  + (size_t)imin(bm * 256 + prow,       M - 1) * lda + skg + koff;
    const u16* asrc1 = A  + (size_t)imin(bm * 256 + prow + 128, M - 1) * lda + skg + koff;
    const u16* bsrc0 = Bt + (size_t)(bn * 256 + prow)       * ldb + skg + koff;
    const u16* bsrc1 = Bt + (size_t)(bn * 256 + prow + 128) * ldb + skg + koff;

    auto STAGE = [&](int s, int k0) {
        gll16(asrc0 + k0, &LA[s][tid * 8]);
        gll16(asrc1 + k0, &LA[s][4096 + tid * 8]);
        gll16(bsrc0 + k0, &LB[s][tid * 8]);
        gll16(bsrc1 + k0, &LB[s][4096 + tid * 8]);
    };

    const int kge = (lg ^ ((lr >> 1) & 3)) * 8;
    int aoff[8], boff[4];
    #pragma unroll
    for (int m = 0; m < 8; ++m) aoff[m] = (wm * 128 + m * 16 + lr) * 32 + kge;
    #pragma unroll
    for (int n = 0; n < 4; ++n) boff[n] = (wn * 64 + n * 16 + lr) * 32 + kge;

    f32x4 acc[8][4] = {};
    short8 af[8], bf[4];

    const int nk = Keff >> 5;
    STAGE(0, 0);
    STAGE(1, 32);
    asm volatile("s_waitcnt vmcnt(4)" ::: "memory");
    asm volatile("s_barrier" ::: "memory");
    __builtin_amdgcn_sched_barrier(0);

    auto BODY = [&](int t, int s, bool doStage) {
        #pragma unroll
        for (int m = 0; m < 8; ++m) af[m] = *(const short8*)(&LA[s][aoff[m]]);
        #pragma unroll
        for (int n = 0; n < 4; ++n) bf[n] = *(const short8*)(&LB[s][boff[n]]);
        asm volatile("s_waitcnt lgkmcnt(0)" ::: "memory");
        __builtin_amdgcn_sched_barrier(0);
        __builtin_amdgcn_s_setprio(1);
        #pragma unroll
        for (int m = 0; m < 4; ++m)
            #pragma unroll
            for (int n = 0; n < 4; ++n)
                acc[m][n] = mfma16(af[m], bf[n], acc[m][n]);
        __builtin_amdgcn_s_setprio(0);
        asm volatile("s_barrier" ::: "memory");
        __builtin_amdgcn_sched_barrier(0);
        if (doStage) STAGE(s, (t + 2) * 32);
        __builtin_amdgcn_s_setprio(1);
        #pragma unroll
        for (int m = 4; m < 8; ++m)
            #pragma unroll
            for (int n = 0; n < 4; ++n)
                acc[m][n] = mfma16(af[m], bf[n], acc[m][n]);
        __builtin_amdgcn_s_setprio(0);
    };

    for (int t = 0; t < nk - 2; ++t) {
        BODY(t, t & 1, true);
        asm volatile("s_waitcnt vmcnt(4)" ::: "memory");
        __builtin_amdgcn_sched_barrier(0);
        asm volatile("s_barrier" ::: "memory");
        __builtin_amdgcn_sched_barrier(0);
    }
    BODY(nk - 2, (nk - 2) & 1, false);
    asm volatile("s_waitcnt vmcnt(0)" ::: "memory");
    __builtin_amdgcn_sched_barrier(0);
    asm volatile("s_barrier" ::: "memory");
    __builtin_amdgcn_sched_barrier(0);
    BODY(nk - 1, (nk - 1) & 1, false);

    #pragma unroll
    for (int m = 0; m < 8; ++m) {
        const int rb = bm * 256 + wm * 128 + m * 16 + lg * 4;
        #pragma unroll
        for (int n = 0; n < 4; ++n) {
            const int col = bn * 256 + wn * 64 + n * 16 + lr;
            const float bvl = (EPI == EPI_PART) ? 0.f : bias[col];
            #pragma unroll
            for (int j = 0; j < 4; ++j) {
                const int r = rb + j;
                if (r >= M) continue;
                const float v = acc[m][n][j] + bvl;
                const size_t oi = (size_t)r * N + col;
                if (EPI == EPI_QKV) {
                    const int q = col >> 10, lc = col & 1023;
                    u16* dst = (q == 0) ? outB : ((q == 1) ? outB2 : outB3);
                    dst[(size_t)r * 1024 + lc] = f2bf(v);
                }
                else if (EPI == EPI_B_RELU_BF16) outB[oi] = f2bf(fmaxf(v, 0.f));
                else if (EPI == EPI_B_RES_F32)   outF[oi] = v + extra[oi];
                else if (EPI == EPI_EMBED)       outF[oi] = v * 32.0f + extra[(size_t)(r % 300) * 1024 + col];
                else if (EPI == EPI_PART)        outF[(size_t)z * M * N + oi] = v;
            }
        }
    }
}

// ==== 128x128 BK=32 RING-3 counted-vmcnt GEMM, 256 threads / 4 waves 2x2 ====
// Requires: N % 128 == 0 (A rows clamped), K % 32 == 0, K/32 >= 4. 1-D grid, XCD swizzle if %8==0.
// Ring-3: slots {0,1,2}; steady-state vmcnt(8) keeps 2 tiles (8 loads) in flight -> ~2.5-iter lead.
template<int EPI>
__global__ void __launch_bounds__(256, 3) gemm_mid(const u16* __restrict__ A, const u16* __restrict__ Bt,
        const float* __restrict__ bias, const float* __restrict__ extra,
        float* outF, u16* outB, u16* outB2, u16* outB3,
        int M, int N, int K, int lda, int ldb)
{
    __shared__ __align__(16) u16 LA[3][128 * 32];   // 8 KB x3
    __shared__ __align__(16) u16 LB[3][128 * 32];   // 8 KB x3  (total 48 KB -> 3 blocks/CU)
    const int tid = threadIdx.x;
    int lin = blockIdx.x;
    const int nwg = gridDim.x;
    if ((nwg & 7) == 0) { const int cpx = nwg >> 3; lin = (lin & 7) * cpx + (lin >> 3); }
    const int ntN = N >> 7;
    const int bm = lin / ntN, bn = lin - (lin / ntN) * ntN;

    const int lane = tid & 63, wid = tid >> 6;
    const int wr = wid >> 1, wc = wid & 1;          // 2 x 2 waves
    const int lg = lane >> 4, lr = lane & 15;

    const int prow = tid >> 2;
    const int skg  = (((tid & 3) ^ ((tid >> 3) & 3)) * 8);
    const u16* asrc0 = A  + (size_t)imin(bm * 128 + prow,      M - 1) * lda + skg;
    const u16* asrc1 = A  + (size_t)imin(bm * 128 + prow + 64, M - 1) * lda + skg;
    const u16* bsrc0 = Bt + (size_t)(bn * 128 + prow)      * ldb + skg;
    const u16* bsrc1 = Bt + (size_t)(bn * 128 + prow + 64) * ldb + skg;

    auto STAGE = [&](int s, int k0) {               // 4 loads per thread, 16B each
        gll16(asrc0 + k0, &LA[s][tid * 8]);
        gll16(asrc1 + k0, &LA[s][2048 + tid * 8]);
        gll16(bsrc0 + k0, &LB[s][tid * 8]);
        gll16(bsrc1 + k0, &LB[s][2048 + tid * 8]);
    };

    const int kge = (lg ^ ((lr >> 1) & 3)) * 8;
    int aoff[4], boff[4];
    #pragma unroll
    for (int m = 0; m < 4; ++m) aoff[m] = (wr * 64 + m * 16 + lr) * 32 + kge;
    #pragma unroll
    for (int n = 0; n < 4; ++n) boff[n] = (wc * 64 + n * 16 + lr) * 32 + kge;

    f32x4 acc[4][4] = {};
    short8 af[4], bf[4];

    const int nk = K >> 5;
    STAGE(0, 0);
    STAGE(1, 32);
    STAGE(2, 64);
    asm volatile("s_waitcnt vmcnt(8)" ::: "memory");   // tile0's 4 loads landed; tiles 1,2 in flight
    asm volatile("s_barrier" ::: "memory");
    __builtin_amdgcn_sched_barrier(0);

    auto BODY = [&](int t, int s, bool doStage) {
        #pragma unroll
        for (int m = 0; m < 4; ++m) af[m] = *(const short8*)(&LA[s][aoff[m]]);
        #pragma unroll
        for (int n = 0; n < 4; ++n) bf[n] = *(const short8*)(&LB[s][boff[n]]);
        asm volatile("s_waitcnt lgkmcnt(0)" ::: "memory");
        __builtin_amdgcn_sched_barrier(0);
        __builtin_amdgcn_s_setprio(1);
        #pragma unroll
        for (int m = 0; m < 2; ++m)
            #pragma unroll
            for (int n = 0; n < 4; ++n)
                acc[m][n] = mfma16(af[m], bf[n], acc[m][n]);
        __builtin_amdgcn_s_setprio(0);
        asm volatile("s_barrier" ::: "memory");              // seals all waves' reads of slot s
        __builtin_amdgcn_sched_barrier(0);
        if (doStage) STAGE(s, (t + 3) * 32);                 // overwrite just-sealed slot with t+3
        __builtin_amdgcn_s_setprio(1);
        #pragma unroll
        for (int m = 2; m < 4; ++m)
            #pragma unroll
            for (int n = 0; n < 4; ++n)
                acc[m][n] = mfma16(af[m], bf[n], acc[m][n]);
        __builtin_amdgcn_s_setprio(0);
    };

    int s = 0;
    for (int t = 0; t < nk - 3; ++t) {
        BODY(t, s, true);
        asm volatile("s_waitcnt vmcnt(8)" ::: "memory");     // tile t+1 landed; t+2,t+3 in flight
        __builtin_amdgcn_sched_barrier(0);
        asm volatile("s_barrier" ::: "memory");
        __builtin_amdgcn_sched_barrier(0);
        s = (s == 2) ? 0 : s + 1;
    }
    BODY(nk - 3, s, false);
    asm volatile("s_waitcnt vmcnt(4)" ::: "memory");         // tile nk-2 landed; nk-1 in flight
    __builtin_amdgcn_sched_barrier(0);
    asm volatile("s_barrier" ::: "memory");
    __builtin_amdgcn_sched_barrier(0);
    s = (s == 2) ? 0 : s + 1;
    BODY(nk - 2, s, false);
    asm volatile("s_waitcnt vmcnt(0)" ::: "memory");         // tile nk-1 landed
    __builtin_amdgcn_sched_barrier(0);
    asm volatile("s_barrier" ::: "memory");
    __builtin_amdgcn_sched_barrier(0);
    s = (s == 2) ? 0 : s + 1;
    BODY(nk - 1, s, false);

    #pragma unroll
    for (int m = 0; m < 4; ++m) {
        const int rb = bm * 128 + wr * 64 + m * 16 + lg * 4;
        #pragma unroll
        for (int n = 0; n < 4; ++n) {
            const int col = bn * 128 + wc * 64 + n * 16 + lr;
            const float bvl = bias[col];
            #pragma unroll
            for (int j = 0; j < 4; ++j) {
                const int r = rb + j;
                if (r >= M) continue;
                const float v = acc[m][n][j] + bvl;
                const size_t oi = (size_t)r * N + col;
                if      (EPI == EPI_B_RES_F32)   outF[oi] = v + extra[oi];
                else if (EPI == EPI_EMBED)       outF[oi] = v * 32.0f + extra[(size_t)(r % 300) * 1024 + col];
                else if (EPI == EPI_B_RELU_BF16) outB[oi] = f2bf(fmaxf(v, 0.f));
                else if (EPI == EPI_QKV) {
                    const int q = col >> 10, lc = col & 1023;
                    u16* dst = (q == 0) ? outB : ((q == 1) ? outB2 : outB3);
                    dst[(size_t)r * 1024 + lc] = f2bf(v);
                }
            }
        }
    }
}

// ---------------- split-K reduce + bias (+tanh) ----------------
template<int TANH>
__global__ void __launch_bounds__(256) redk_kernel(const float* __restrict__ part,
        const float* __restrict__ bias, float* outF, u16* outB, int M, int N, int Z)
{
    const int i = blockIdx.x * 256 + threadIdx.x;
    if (i >= M * N) return;
    const int col = i % N;
    float s = 0.f;
    for (int z = 0; z < Z; ++z) s += part[(size_t)z * M * N + i];
    s += bias[col];
    if (TANH) outB[i] = f2bf(tanhf(s));
    else      outF[i] = s;
}

// ------ attention: scores + softmax -> P bf16 (512 thr / 8 waves, LDS-bounce coalesced) ------
__global__ void __launch_bounds__(512) attn_scores_kernel(const u16* __restrict__ Qb,
        const u16* __restrict__ Kb, u16* __restrict__ P)
{
    __shared__ __align__(16) u16 Ks[304 * 128];     // 77824 B, XOR-swizzled rows
    __shared__ __align__(16) u16 Ps[8][16][TP];     // 81920 B per-wave P bounce (tot 159744)
    const int bh = blockIdx.x, b = bh >> 3, h = bh & 7;
    const int tid = threadIdx.x, lane = tid & 63, wid = tid >> 6;
    const int lg = lane >> 4, lr = lane & 15;

    for (int c = tid; c < 304 * 16; c += 512) {
        const int kv = c >> 4, part = c & 15;
        const int tok = b * 300 + imin(kv, 299);
        const short8 v = *(const short8*)(Kb + (size_t)tok * 1024 + h * 128 + part * 8);
        int byte_ = kv * 256 + part * 16;
        byte_ ^= (kv & 7) << 4;
        *(short8*)((char*)Ks + byte_) = v;
    }
    __syncthreads();

    const float scale = 0.08838834764831845f;   // 1/sqrt(128)
    for (int qt = wid; qt < NQT; qt += 8) {
        f32x4 acc[NQT] = {};
        const int qtok = b * 300 + imin(qt * 16 + lr, 299);
        const u16* qrow = Qb + (size_t)qtok * 1024 + h * 128;
        #pragma unroll
        for (int kk = 0; kk < 4; ++kk) {
            const short8 aq = *(const short8*)(qrow + kk * 32 + lg * 8);
            #pragma unroll
            for (int nt = 0; nt < NQT; ++nt) {
                const int kvrow = nt * 16 + lr;
                int byte_ = kvrow * 256 + kk * 64 + lg * 16;
                byte_ ^= (kvrow & 7) << 4;
                const short8 bk = *(const short8*)((char*)Ks + byte_);
                acc[nt] = mfma16(aq, bk, acc[nt]);
            }
        }
        const int sw = lg << 3;     // ((row>>2)&3)<<3 with row = lg*4+j
        #pragma unroll
        for (int j = 0; j < 4; ++j) {
            float vals[NQT];
            float m = -1e30f;
            #pragma unroll
            for (int nt = 0; nt < NQT; ++nt) {
                float s = acc[nt][j] * scale;
                if (nt * 16 + lr >= 300) s = -1e30f;
                vals[nt] = s;
                m = fmaxf(m, s);
            }
            #pragma unroll
            for (int o = 1; o < 16; o <<= 1) m = fmaxf(m, __shfl_xor(m, o));
            float sum = 0.f;
            #pragma unroll
            for (int nt = 0; nt < NQT; ++nt) { const float e = __expf(vals[nt] - m); vals[nt] = e; sum += e; }
            #pragma unroll
            for (int o = 1; o < 16; o <<= 1) sum += __shfl_xor(sum, o);
            const float inv = 1.0f / sum;
            const int row = lg * 4 + j;
            #pragma unroll
            for (int nt = 0; nt < NQT; ++nt) Ps[wid][row][(nt * 16 + lr) ^ sw] = f2bf(vals[nt] * inv);
            Ps[wid][row][(304 + lr) ^ sw] = 0;   // zero kv pad 304..319
        }
        // wave-local flush (NO __syncthreads: waves have unequal qt counts)
        asm volatile("s_waitcnt lgkmcnt(0)" ::: "memory");
        __builtin_amdgcn_sched_barrier(0);
        // coalesced copy-out: 16 rows x 320 u16 = 640 short8
        #pragma unroll
        for (int it = 0; it < 10; ++it) {
            const int idx = it * 64 + lane;
            const int row = idx / 40, c8 = idx - row * 40;
            const int swr = ((row >> 2) & 3) << 3;
            const short8 v8 = *(const short8*)(&Ps[wid][row][(c8 * 8) ^ swr]);
            const int q = qt * 16 + row;
            if (q < 300) *(short8*)(P + ((size_t)bh * 300 + q) * TP + c8 * 8) = v8;
        }
    }
}

// ------ attention: O = P @ V (512 thr / 8 waves, LDS-bounce coalesced) ------
__global__ void __launch_bounds__(512) attn_pv_kernel(const u16* __restrict__ P,
        const u16* __restrict__ Vb, u16* __restrict__ O)
{
    __shared__ __align__(16) u16 Vs[128 * TP];      // 81920 B, V^T XOR-swizzled rows
    __shared__ __align__(16) u16 Os[8][16][128];    // 32768 B per-wave O bounce
    const int bh = blockIdx.x, b = bh >> 3, h = bh & 7;
    const int tid = threadIdx.x, lane = tid & 63, wid = tid >> 6;
    const int lg = lane >> 4, lr = lane & 15;

    for (int c = tid; c < 304 * 16; c += 512) {
        const int kv = c >> 4, dp = c & 15;
        const int tok = b * 300 + imin(kv, 299);
        const short8 v = *(const short8*)(Vb + (size_t)tok * 1024 + h * 128 + dp * 8);
        #pragma unroll
        for (int jj = 0; jj < 8; ++jj) {
            const int d = dp * 8 + jj;
            int byte_ = d * (TP * 2) + kv * 2;
            byte_ ^= (d & 7) << 4;
            *(u16*)((char*)Vs + byte_) = (u16)v[jj];
        }
    }
    for (int c = tid; c < 128 * 16; c += 512) {     // zero kv pad 304..319
        const int d = c >> 4, kv = 304 + (c & 15);
        int byte_ = d * (TP * 2) + kv * 2;
        byte_ ^= (d & 7) << 4;
        *(u16*)((char*)Vs + byte_) = 0;
    }
    __syncthreads();

    for (int qt = wid; qt < NQT; qt += 8) {
        f32x4 acc[8] = {};
        const int q = imin(qt * 16 + lr, 299);
        const u16* prow = P + ((size_t)bh * 300 + q) * TP;
        #pragma unroll
        for (int kk = 0; kk < 10; ++kk) {
            const short8 ap = *(const short8*)(prow + kk * 32 + lg * 8);
            #pragma unroll
            for (int nt = 0; nt < 8; ++nt) {
                const int d = nt * 16 + lr;
                int byte_ = d * (TP * 2) + kk * 64 + lg * 16;
                byte_ ^= (d & 7) << 4;
                const short8 bv8 = *(const short8*)((char*)Vs + byte_);
                acc[nt] = mfma16(ap, bv8, acc[nt]);
            }
        }
        const int sw = lg << 3;
        #pragma unroll
        for (int nt = 0; nt < 8; ++nt)
            #pragma unroll
            for (int j = 0; j < 4; ++j)
                Os[wid][lg * 4 + j][(nt * 16 + lr) ^ sw] = f2bf(acc[nt][j]);
        asm volatile("s_waitcnt lgkmcnt(0)" ::: "memory");
        __builtin_amdgcn_sched_barrier(0);
        #pragma unroll
        for (int it = 0; it < 4; ++it) {
            const int idx = it * 64 + lane;
            const int row = idx >> 4, c8 = idx & 15;
            const int swr = ((row >> 2) & 3) << 3;
            const short8 v8 = *(const short8*)(&Os[wid][row][(c8 * 8) ^ swr]);
            const int qq = qt * 16 + row;
            if (qq < 300)
                *(short8*)(O + ((size_t)(b * 300 + qq)) * 1024 + h * 128 + c8 * 8) = v8;
        }
    }
}

// ---------------- classifier tail ----------------
__global__ void __launch_bounds__(256) logits_kernel(const float* __restrict__ a1,
        const float* __restrict__ cw2, const float* __restrict__ cb2, float* __restrict__ out)
{
    const int tok = blockIdx.x * 4 + (threadIdx.x >> 6);
    const int lane = threadIdx.x & 63;
    if (tok >= NTOK) return;
    const float v0 = a1[(size_t)tok * 128 + lane];
    const float v1 = a1[(size_t)tok * 128 + 64 + lane];
    #pragma unroll
    for (int hp = 0; hp < 4; ++hp) {
        float s = v0 * cw2[lane * 4 + hp] + v1 * cw2[(64 + lane) * 4 + hp];
        #pragma unroll
        for (int o = 1; o < 64; o <<= 1) s += __shfl_xor(s, o);
        if (lane == 0) out[(size_t)tok * 4 + hp] = s + cb2[hp];
    }
}

__global__ void __launch_bounds__(512) softmaxT_kernel(const float* __restrict__ lgt,
        float* __restrict__ alpha, float* __restrict__ outAlpha)
{
    const int bh = blockIdx.x;           // b*4 + hop
    const int b = bh >> 2, hp = bh & 3;
    const int t = threadIdx.x;
    const float v = (t < 300) ? lgt[((size_t)(b * 300 + t)) * 4 + hp] : -1e30f;
    float m = v;
    #pragma unroll
    for (int o = 1; o < 64; o <<= 1) m = fmaxf(m, __shfl_xor(m, o));
    __shared__ float rm[8], rs[8];
    const int lane = t & 63, wid = t >> 6;
    if (lane == 0) rm[wid] = m;
    __syncthreads();
    m = rm[0];
    #pragma unroll
    for (int i = 1; i < 8; ++i) m = fmaxf(m, rm[i]);
    const float e = (t < 300) ? __expf(v - m) : 0.f;
    float s = e;
    #pragma unroll
    for (int o = 1; o < 64; o <<= 1) s += __shfl_xor(s, o);
    if (lane == 0) rs[wid] = s;
    __syncthreads();
    s = rs[0] + rs[1] + rs[2] + rs[3] + rs[4] + rs[5] + rs[6] + rs[7];
    if (t < 300) {
        const float a = e / s;
        alpha[(size_t)bh * 300 + t] = a;
        outAlpha[(size_t)bh * 300 + t] = a;
    }
}

__global__ void __launch_bounds__(256) pool_kernel(const float* __restrict__ alpha,
        const float* __restrict__ xln, float* __restrict__ wsp)
{
    const int bh = blockIdx.x, b = bh >> 2;
    const int d = blockIdx.y * 256 + threadIdx.x;
    const float* xp = xln + (size_t)b * 300 * 1024 + d;
    const float* al = alpha + (size_t)bh * 300;
    float acc = 0.f;
    for (int t = 0; t < 300; ++t) acc += al[t] * xp[(size_t)t * 1024];
    wsp[(size_t)bh * 1024 + d] = acc;
}

// =====================================================================
extern "C" void kernel_launch(void* const* d_in, const int* in_sizes, int n_in,
                              void* d_out, int out_size, void* d_ws, size_t ws_size,
                              hipStream_t stream)
{
    const float* rgb     = (const float*)d_in[0];
    const float* aud     = (const float*)d_in[1];
    const float* embed_W = (const float*)d_in[2];
    const float* embed_b = (const float*)d_in[3];
    const float* Wq      = (const float*)d_in[4];
    const float* bq      = (const float*)d_in[5];
    const float* Wk      = (const float*)d_in[6];
    const float* bk      = (const float*)d_in[7];
    const float* Wv      = (const float*)d_in[8];
    const float* bv      = (const float*)d_in[9];
    const float* Wo      = (const float*)d_in[10];
    const float* bo      = (const float*)d_in[11];
    const float* ln1_a   = (const float*)d_in[12];
    const float* ln1_b   = (const float*)d_in[13];
    const float* W1f     = (const float*)d_in[14];
    const float* b1f     = (const float*)d_in[15];
    const float* W2f     = (const float*)d_in[16];
    const float* b2f     = (const float*)d_in[17];
    const float* ln2_a   = (const float*)d_in[18];
    const float* ln2_b   = (const float*)d_in[19];
    const float* fn_a    = (const float*)d_in[20];
    const float* fn_b    = (const float*)d_in[21];
    const float* cw1     = (const float*)d_in[22];
    const float* cb1     = (const float*)d_in[23];
    const float* cw2     = (const float*)d_in[24];
    const float* cb2     = (const float*)d_in[25];
    const float* cw3     = (const float*)d_in[26];
    const float* cb3     = (const float*)d_in[27];
    const float* cw4     = (const float*)d_in[28];
    const float* cb4     = (const float*)d_in[29];

    const bool bigS = ws_size >= ((size_t)238 << 20);   // host-side constant per process
    const size_t Ssz = bigS ? (size_t)NTOK * DFF * 2 : (size_t)256 * 300 * TP * 2;

    char* base = (char*)d_ws;
    size_t off = 0;
    auto alloc = [&](size_t bytes) -> char* {
        char* p = base + off; off += (bytes + 255) & ~(size_t)255; return p; };

    float* x    = (float*)alloc((size_t)NTOK * DD * 4);        // 39.3 MB (c3T aliases after final LN)
    float* pe   = (float*)alloc((size_t)TT * DD * 4);          //  1.2 MB
    u16*  hbuf  = (u16*) alloc((size_t)NTOK * DD * 2);         // 19.7 MB (Ob aliases)
    u16*  Qb    = (u16*) alloc((size_t)NTOK * DD * 2);         // 19.7 MB (xln aliases Qb+Kb)
    u16*  Kb    = (u16*) alloc((size_t)NTOK * DD * 2);         // 19.7 MB
    u16*  Vb    = (u16*) alloc((size_t)NTOK * DD * 2);         // 19.7 MB (xlnb aliases)
    u16*  S     = (u16*) alloc(Ssz);                           // 49.2 or 78.6 MB shared region
    float* lgts = (float*)alloc((size_t)NTOK * 4 * 4);
    float* alph = (float*)alloc((size_t)128 * 300 * 4);
    float* wsp  = (float*)alloc((size_t)32 * 4096 * 4);
    u16*  wsb   = (u16*) alloc((size_t)32 * 4096 * 2);
    u16*  t3b   = (u16*) alloc((size_t)32 * 4096 * 2);
    float* bqkv = (float*)alloc((size_t)4 * 3072 * 4);         // fused QKV bias
    u16*  eWt   = (u16*) alloc((size_t)1024 * 1152 * 2);       //  2.4 MB
    u16*  WqkvT = (u16*) alloc((size_t)3 * 1024 * 1024 * 2);   //  6.3 MB (fused, per-layer reuse)
    u16*  WoT   = (u16*) alloc((size_t)1024 * 1024 * 2);
    u16*  W1T   = (u16*) alloc((size_t)DFF * DD * 2);          //  8.4 MB [DFF rows, DD]
    u16*  W2T   = (u16*) alloc((size_t)DD * DFF * 2);          //  8.4 MB [DD rows, DFF]
    u16*  c1T   = (u16*) alloc((size_t)128 * 1024 * 2);
    if (off > ws_size) return;   // loud failure if insufficient

    u16*  featsb = S;             // 22.1 MB, dead after embed GEMM
    u16*  pbuf   = S;             // 49.2 MB, attn P for all 256 bh (dead outside attn)
    u16*  midc   = S;             // FFN activation (full DFF if bigS, else half)
    u16*  Ob     = hbuf;          // attention output (hbuf dead after QKV gemm)
    float* xln   = (float*)Qb;    // final-LN f32 output: spans Qb+Kb (both dead)
    u16*  xlnb   = Vb;            // final-LN bf16 output (Vb dead)
    float* a1    = (float*)S;     // 4.9 MB, classifier phase
    u16*  c3T    = (u16*)x;       // 32.0 MB  <= 39.3 (x dead after final LN)
    u16*  c4T    = S;             // 31.6 MB  (written after logits; a1 dead)
    float* part  = (float*)hbuf;  // classifier split-K partials (hbuf dead in classifier)
    float* outv     = (float*)d_out;
    float* outAlpha = outv + (size_t)32 * NCLS;

    const dim3 blk(256);

    pe_kernel<<<(TT * DD + 255) / 256, blk, 0, stream>>>(pe);
    feats_kernel<<<(int)(((size_t)NTOK * FIN + 255) / 256), blk, 0, stream>>>(rgb, aud, featsb);
    qkvbias_kernel<<<(4 * 3072 + 255) / 256, blk, 0, stream>>>(bq, bk, bv, bqkv);

    auto wconv = [&](const float* W, u16* Wt, int K, int N) {
        dim3 g((N + 31) / 32, (K + 31) / 32);
        wconv_kernel<<<g, dim3(32, 8), 0, stream>>>(W, Wt, K, N);
    };
    wconv(embed_W, eWt, FIN, DD);
    wconv(cw1, c1T, DD, DATT);

    // embed: x = (feats @ W + b)*sqrt(D) + PE   (gemm_mid ring-3, grid 600 %8==0)
    gemm_mid<EPI_EMBED><<<600, blk, 0, stream>>>(featsb, eWt, embed_b, pe, x,
            nullptr, nullptr, nullptr, NTOK, DD, FIN, FIN, FIN);

    for (int i = 0; i < 4; ++i) {
        wconv3_kernel<<<dim3(32, 32, 3), dim3(32, 8), 0, stream>>>(
                Wq + (size_t)i * DD * DD, Wk + (size_t)i * DD * DD, Wv + (size_t)i * DD * DD, WqkvT);
        wconv(Wo  + (size_t)i * DD * DD,  WoT, DD, DD);
        wconv(W1f + (size_t)i * DD * DFF, W1T, DD, DFF);
        wconv(W2f + (size_t)i * DFF * DD, W2T, DFF, DD);

        ln_kernel<0><<<NTOK, blk, 0, stream>>>(x, ln1_a + (size_t)i * DD, ln1_b + (size_t)i * DD, hbuf, nullptr);
        // fused QKV: gemm_mid ring-3, grid 75*24 = 1800 (%8==0)
        gemm_mid<EPI_QKV><<<1800, blk, 0, stream>>>(hbuf, WqkvT, bqkv + (size_t)i * 3072, nullptr,
                nullptr, Qb, Kb, Vb, NTOK, 3072, DD, DD, DD);
        attn_scores_kernel<<<256, dim3(512), 0, stream>>>(Qb, Kb, pbuf);
        attn_pv_kernel<<<256, dim3(512), 0, stream>>>(pbuf, Vb, Ob);   // Ob = hbuf (dead now)
        // Wo + residual: gemm_mid ring-3, grid 600
        gemm_mid<EPI_B_RES_F32><<<600, blk, 0, stream>>>(Ob, WoT, bo + (size_t)i * DD, x, x,
                nullptr, nullptr, nullptr, NTOK, DD, DD, DD, DD);
        ln_kernel<0><<<NTOK, blk, 0, stream>>>(x, ln2_a + (size_t)i * DD, ln2_b + (size_t)i * DD, hbuf, nullptr);
        if (bigS) {
            // FFN1: gemm_mid ring-3, grid 75*32 = 2400 (%8==0); FFN2: gemm_mid, grid 600, K=4096
            gemm_mid<EPI_B_RELU_BF16><<<2400, blk, 0, stream>>>(hbuf, W1T, b1f + (size_t)i * DFF,
                    nullptr, nullptr, midc, nullptr, nullptr, NTOK, DFF, DD, DD, DD);
            gemm_mid<EPI_B_RES_F32><<<600, blk, 0, stream>>>(midc, W2T, b2f + (size_t)i * DD, x, x,
                    nullptr, nullptr, nullptr, NTOK, DD, DFF, DFF, DFF);
        } else {
            for (int h = 0; h < 2; ++h) {
                gemm_big<EPI_B_RELU_BF16><<<304, dim3(512), 0, stream>>>(hbuf, W1T + (size_t)h * 2048 * DD,
                        b1f + (size_t)i * DFF + h * 2048, nullptr, nullptr, midc, nullptr, nullptr,
                        NTOK, 2048, DD, DD, DD, 0);
                if (h == 0)
                    gemm_k<EPI_B_RES_F32, 1><<<dim3(8, 75), blk, 0, stream>>>(midc, W2T + (size_t)h * 2048,
                            b2f + (size_t)i * DD, x, x, nullptr, nullptr, nullptr, NTOK, DD, 2048, 2048, DFF, 0);
                else
                    gemm_k<EPI_ACC_F32, 1><<<dim3(8, 75), blk, 0, stream>>>(midc, W2T + (size_t)h * 2048,
                            b2f + (size_t)i * DD, x, x, nullptr, nullptr, nullptr, NTOK, DD, 2048, 2048, DFF, 0);
            }
        }
    }

    ln_kernel<1><<<NTOK, blk, 0, stream>>>(x, fn_a, fn_b, xlnb, xln);
    wconv(cw3, c3T, 4096, DFF);                               // x dead -> c3T
    gemm_k<EPI_B_TANH_F32, 0><<<dim3(1, 75), blk, 0, stream>>>(xlnb, c1T, cb1, nullptr, a1,
            nullptr, nullptr, nullptr, NTOK, DATT, DD, DD, DD, 0);
    logits_kernel<<<2400, blk, 0, stream>>>(a1, cw2, cb2, lgts);
    wconv(cw4, c4T, DFF, NCLS);                               // a1 dead -> c4T
    softmaxT_kernel<<<128, dim3(512), 0, stream>>>(lgts, alph, outAlpha);
    pool_kernel<<<dim3(128, 4), blk, 0, stream>>>(alph, xln, wsp);
    f2bf_kernel<<<(32 * 4096 + 255) / 256, blk, 0, stream>>>(wsp, wsb, 32 * 4096);

    // classifier GEMMs: split-K (Z=8, Kc=512), deterministic reduce
    gemm_k<EPI_PART, 0><<<dim3(32, 1, 8), blk, 0, stream>>>(wsb, c3T, nullptr, nullptr, part,
            nullptr, nullptr, nullptr, 32, 4096, 4096, 4096, 4096, 512);
    redk_kernel<1><<<(32 * 4096 + 255) / 256, blk, 0, stream>>>(part, cb3, nullptr, t3b, 32, 4096, 8);
    gemm_k<EPI_PART, 0><<<dim3(31, 1, 8), blk, 0, stream>>>(t3b, c4T, nullptr, nullptr, part,
            nullptr, nullptr, nullptr, 32, NCLS, 4096, 4096, 4096, 512);
    redk_kernel<0><<<(32 * NCLS + 255) / 256, blk, 0, stream>>>(part, cb4, outv, nullptr, 32, NCLS, 8);
}

// Round 15
// 2077.418 us; speedup vs baseline: 1.0135x; 1.0135x over previous
//
#include <hip/hip_runtime.h>
#include <stdint.h>

#define NTOK 9600
#define TT   300
#define DD   1024
#define HH   8
#define DFF  4096
#define FIN  1152
#define DATT 128
#define NCLS 3862
#define TP   320   // kv padded for PV k-steps
#define NQT  19    // ceil(304/16) tiles of 16

typedef unsigned short u16;
typedef __attribute__((ext_vector_type(8))) short short8;
typedef __attribute__((ext_vector_type(4))) float f32x4;

__device__ __forceinline__ int imin(int a, int b){ return a < b ? a : b; }

__device__ __forceinline__ u16 f2bf(float f){
    union { float f; uint32_t u; } v; v.f = f;
    uint32_t u = v.u;
    return (u16)((u + 0x7fffu + ((u >> 16) & 1u)) >> 16);
}

__device__ __forceinline__ f32x4 mfma16(short8 a, short8 b, f32x4 c){
    return __builtin_amdgcn_mfma_f32_16x16x32_bf16(a, b, c, 0, 0, 0);
}

// async global->LDS, 16B per lane. LDS dest must be wave-uniform base + lane*16 (linear).
__device__ __forceinline__ void gll16(const void* g, void* l){
    __builtin_amdgcn_global_load_lds((const __attribute__((address_space(1))) void*)g,
                                     (__attribute__((address_space(3))) void*)l, 16, 0, 0);
}

// ---------------- PE table ----------------
__global__ void __launch_bounds__(256) pe_kernel(float* __restrict__ pe)
{
    const int i = blockIdx.x * 256 + threadIdx.x;
    if (i >= TT * DD) return;
    const int t = i >> 10, d = i & 1023;
    const float fr = expf(-(float)(d & ~1) * (9.210340371976184f / 1024.0f));
    const float ang = (float)t * fr;
    pe[i] = (d & 1) ? cosf(ang) : sinf(ang);
}

// ---------------- feats concat + /255 -> bf16 ----------------
__global__ void __launch_bounds__(256) feats_kernel(const float* __restrict__ rgb,
        const float* __restrict__ aud, u16* __restrict__ out)
{
    const long i = (long)blockIdx.x * 256 + threadIdx.x;
    if (i >= (long)NTOK * FIN) return;
    const int row = (int)(i / FIN), c = (int)(i % FIN);
    const float v = (c < 1024) ? rgb[(size_t)row * 1024 + c] : aud[(size_t)row * 128 + (c - 1024)];
    out[i] = f2bf(v * (1.0f / 255.0f));
}

// ---------------- weight transpose + convert: W[K,N] f32 -> Wt[N,K] bf16 ----------------
__global__ void __launch_bounds__(256) wconv_kernel(const float* __restrict__ W,
        u16* __restrict__ Wt, int K, int N)
{
    __shared__ float tile[32][33];
    const int k0 = blockIdx.y * 32, n0 = blockIdx.x * 32;
    const int tx = threadIdx.x, ty = threadIdx.y;   // 32 x 8
    #pragma unroll
    for (int i = 0; i < 4; ++i) {
        const int k = k0 + ty + i * 8, n = n0 + tx;
        tile[ty + i * 8][tx] = (k < K && n < N) ? W[(size_t)k * N + n] : 0.f;
    }
    __syncthreads();
    #pragma unroll
    for (int i = 0; i < 4; ++i) {
        const int n = n0 + ty + i * 8, k = k0 + tx;
        if (n < N && k < K) Wt[(size_t)n * K + k] = f2bf(tile[tx][ty + i * 8]);
    }
}

// ---------------- batched x3 (QKV) weight transpose: 1024x1024 each ----------------
__global__ void __launch_bounds__(256) wconv3_kernel(const float* __restrict__ W0,
        const float* __restrict__ W1, const float* __restrict__ W2, u16* __restrict__ Wt)
{
    __shared__ float tile[32][33];
    const float* W = (blockIdx.z == 0) ? W0 : ((blockIdx.z == 1) ? W1 : W2);
    u16* dst = Wt + (size_t)blockIdx.z * DD * DD;
    const int k0 = blockIdx.y * 32, n0 = blockIdx.x * 32;
    const int tx = threadIdx.x, ty = threadIdx.y;   // 32 x 8
    #pragma unroll
    for (int i = 0; i < 4; ++i)
        tile[ty + i * 8][tx] = W[(size_t)(k0 + ty + i * 8) * DD + n0 + tx];
    __syncthreads();
    #pragma unroll
    for (int i = 0; i < 4; ++i)
        dst[(size_t)(n0 + ty + i * 8) * DD + k0 + tx] = f2bf(tile[tx][ty + i * 8]);
}

// ---------------- f32 -> bf16 ----------------
__global__ void __launch_bounds__(256) f2bf_kernel(const float* __restrict__ in,
        u16* __restrict__ out, int n)
{
    const int i = blockIdx.x * 256 + threadIdx.x;
    if (i < n) out[i] = f2bf(in[i]);
}

// ---------------- fused QKV bias gather: [4][3072] ----------------
__global__ void __launch_bounds__(256) qkvbias_kernel(const float* __restrict__ bq,
        const float* __restrict__ bk, const float* __restrict__ bv, float* __restrict__ out)
{
    const int i = blockIdx.x * 256 + threadIdx.x;
    if (i >= 4 * 3072) return;
    const int l = i / 3072, c = i % 3072;
    float v;
    if      (c < 1024) v = bq[l * 1024 + c];
    else if (c < 2048) v = bk[l * 1024 + c - 1024];
    else               v = bv[l * 1024 + c - 2048];
    out[i] = v;
}

// ---------------- LayerNorm (ddof=1, a*(x-m)/(std+eps)+b) ----------------
template<int WF>
__global__ void __launch_bounds__(256) ln_kernel(const float* __restrict__ xin,
        const float* __restrict__ ga, const float* __restrict__ gb,
        u16* __restrict__ ob, float* of)
{
    const int row = blockIdx.x, t = threadIdx.x;
    const float4 xv = *(const float4*)(xin + (size_t)row * 1024 + t * 4);
    float s1 = xv.x + xv.y + xv.z + xv.w;
    float s2 = xv.x * xv.x + xv.y * xv.y + xv.z * xv.z + xv.w * xv.w;
    #pragma unroll
    for (int o = 1; o < 64; o <<= 1) { s1 += __shfl_xor(s1, o); s2 += __shfl_xor(s2, o); }
    __shared__ float r1[4], r2[4];
    const int lane = t & 63, wid = t >> 6;
    if (lane == 0) { r1[wid] = s1; r2[wid] = s2; }
    __syncthreads();
    s1 = r1[0] + r1[1] + r1[2] + r1[3];
    s2 = r2[0] + r2[1] + r2[2] + r2[3];
    const float mean = s1 * (1.0f / 1024.0f);
    const float var  = (s2 - 1024.0f * mean * mean) * (1.0f / 1023.0f);
    const float inv  = 1.0f / (sqrtf(fmaxf(var, 0.f)) + 1e-6f);
    const float4 av  = *(const float4*)(ga + t * 4);
    const float4 bv  = *(const float4*)(gb + t * 4);
    const float y0 = av.x * (xv.x - mean) * inv + bv.x;
    const float y1 = av.y * (xv.y - mean) * inv + bv.y;
    const float y2 = av.z * (xv.z - mean) * inv + bv.z;
    const float y3 = av.w * (xv.w - mean) * inv + bv.w;
    ushort4 o4; o4.x = f2bf(y0); o4.y = f2bf(y1); o4.z = f2bf(y2); o4.w = f2bf(y3);
    *(ushort4*)(ob + (size_t)row * 1024 + t * 4) = o4;
    if (WF) {
        float4 yo; yo.x = y0; yo.y = y1; yo.z = y2; yo.w = y3;
        *(float4*)(of + (size_t)row * 1024 + t * 4) = yo;
    }
}

// ---------------- epilogue codes ----------------
#define EPI_EMBED        0
#define EPI_QKV          1   // route col>>10 to outB/outB2/outB3 (stride 1024)
#define EPI_B_RELU_BF16  2
#define EPI_B_RES_F32    3
#define EPI_B_TANH_F32   4
#define EPI_ACC_F32      5   // outF = v + extra (no bias; FFN2 second half)
#define EPI_PART         6   // partials for split-K: outF[z*M*N + oi] = v

// ---- generic bf16 MFMA GEMM: C = A[M,K] * Bt[N,K]^T (128x128, 2-phase dbuf; classifier) ----
template<int EPI, int SWZ>
__global__ void __launch_bounds__(256) gemm_k(const u16* __restrict__ A, const u16* __restrict__ Bt,
        const float* __restrict__ bias, const float* extra,
        float* outF, u16* outB, u16* outB2, u16* outB3, int M, int N, int K,
        int lda, int ldb, int kchunk)
{
    __shared__ __align__(16) u16 As[2][4096];
    __shared__ __align__(16) u16 Bs[2][4096];
    const int tid = threadIdx.x;
    int bm, bn;
    if (SWZ) {
        int lin = blockIdx.y * gridDim.x + blockIdx.x;
        const int nwg = gridDim.x * gridDim.y;
        const int cpx = nwg >> 3;
        lin = (lin & 7) * cpx + (lin >> 3);
        bm = lin / gridDim.x;
        bn = lin - bm * gridDim.x;
    } else {
        bm = blockIdx.y; bn = blockIdx.x;
    }
    const int lane = tid & 63, wid = tid >> 6;
    const int lg = lane >> 4, lr = lane & 15;
    const int wr = wid >> 1, wc = wid & 1;

    int koff = 0, Keff = K;
    if (kchunk > 0) { koff = blockIdx.z * kchunk; Keff = kchunk; }

    const int srow = tid >> 2;
    const int skc  = (tid & 3) * 8;
    const u16* ap0 = A  + (size_t)imin(bm * 128 + srow,      M - 1) * lda + skc + koff;
    const u16* ap1 = A  + (size_t)imin(bm * 128 + srow + 64, M - 1) * lda + skc + koff;
    const u16* bp0 = Bt + (size_t)imin(bn * 128 + srow,      N - 1) * ldb + skc + koff;
    const u16* bp1 = Bt + (size_t)imin(bn * 128 + srow + 64, N - 1) * ldb + skc + koff;

    f32x4 acc[4][4] = {};

    auto STAGE = [&](int b, int k0) {
        gll16(ap0 + k0, &As[b][tid * 8]);
        gll16(ap1 + k0, &As[b][2048 + tid * 8]);
        gll16(bp0 + k0, &Bs[b][tid * 8]);
        gll16(bp1 + k0, &Bs[b][2048 + tid * 8]);
    };
    auto COMPUTE = [&](int b) {
        short8 af[4], bf[4];
        #pragma unroll
        for (int m = 0; m < 4; ++m)
            af[m] = *(const short8*)(&As[b][(wr * 64 + m * 16 + lr) * 32 + lg * 8]);
        #pragma unroll
        for (int n = 0; n < 4; ++n)
            bf[n] = *(const short8*)(&Bs[b][(wc * 64 + n * 16 + lr) * 32 + lg * 8]);
        #pragma unroll
        for (int m = 0; m < 4; ++m)
            #pragma unroll
            for (int n = 0; n < 4; ++n)
                acc[m][n] = mfma16(af[m], bf[n], acc[m][n]);
    };

    STAGE(0, 0);
    __syncthreads();
    int cur = 0;
    for (int k0 = 32; k0 < Keff; k0 += 32) {
        STAGE(cur ^ 1, k0);
        COMPUTE(cur);
        __syncthreads();
        cur ^= 1;
    }
    COMPUTE(cur);

    #pragma unroll
    for (int m = 0; m < 4; ++m) {
        const int rb = bm * 128 + wr * 64 + m * 16 + lg * 4;
        #pragma unroll
        for (int n = 0; n < 4; ++n) {
            const int col = bn * 128 + wc * 64 + n * 16 + lr;
            if (col >= N) continue;
            const float bvl = (EPI == EPI_PART || EPI == EPI_ACC_F32) ? 0.f : bias[col];
            #pragma unroll
            for (int j = 0; j < 4; ++j) {
                const int r = rb + j;
                if (r >= M) continue;
                const float v = acc[m][n][j];
                const size_t oi = (size_t)r * N + col;
                if      (EPI == EPI_EMBED)       outF[oi] = (v + bvl) * 32.0f + extra[(size_t)(r % 300) * 1024 + col];
                else if (EPI == EPI_QKV) {
                    const int q = col >> 10, lc = col & 1023;
                    u16* dst = (q == 0) ? outB : ((q == 1) ? outB2 : outB3);
                    dst[(size_t)r * 1024 + lc] = f2bf(v + bvl);
                }
                else if (EPI == EPI_B_RELU_BF16) outB[oi] = f2bf(fmaxf(v + bvl, 0.f));
                else if (EPI == EPI_B_RES_F32)   outF[oi] = v + bvl + extra[oi];
                else if (EPI == EPI_B_TANH_F32)  outF[oi] = tanhf(v + bvl);
                else if (EPI == EPI_ACC_F32)     outF[oi] = v + extra[oi];
                else if (EPI == EPI_PART)        outF[(size_t)blockIdx.z * M * N + oi] = v;
            }
        }
    }
}

// ==== 256x256 BK=32 ring-2 counted-vmcnt GEMM, 512 threads (small-ws fallback only) ====
template<int EPI>
__global__ void __launch_bounds__(512, 2) gemm_big(const u16* __restrict__ A, const u16* __restrict__ Bt,
        const float* __restrict__ bias, const float* __restrict__ extra,
        float* outF, u16* outB, u16* outB2, u16* outB3,
        int M, int N, int K, int lda, int ldb, int kchunk)
{
    __shared__ __align__(16) u16 LA[2][256 * 32];
    __shared__ __align__(16) u16 LB[2][256 * 32];
    const int tid = threadIdx.x;
    int lin = blockIdx.x;
    const int nwg = gridDim.x;
    if ((nwg & 7) == 0) { const int cpx = nwg >> 3; lin = (lin & 7) * cpx + (lin >> 3); }
    int z = 0;
    if (kchunk > 0) { z = lin & 1; lin >>= 1; }
    const int ntN = N >> 8;
    const int bm = lin / ntN, bn = lin - (lin / ntN) * ntN;
    const int koff = z * kchunk;
    const int Keff = (kchunk > 0) ? kchunk : K;

    const int lane = tid & 63, wid = tid >> 6;
    const int wm = wid >> 2, wn = wid & 3;
    const int lg = lane >> 4, lr = lane & 15;

    const int prow = tid >> 2;
    const int skg  = (((tid & 3) ^ ((tid >> 3) & 3)) * 8);
    const u16* asrc0 = A  + (size_t)imin(bm * 256 + prow,       M - 1) * lda + skg + koff;
    const u16* asrc1 = A  + (size_t)imin(bm * 256 + prow + 128, M - 1) * lda + skg + koff;
    const u16* bsrc0 = Bt + (size_t)(bn * 256 + prow)       * ldb + skg + koff;
    const u16* bsrc1 = Bt + (size_t)(bn * 256 + prow + 128) * ldb + skg + koff;

    auto STAGE = [&](int s, int k0) {
        gll16(asrc0 + k0, &LA[s][tid * 8]);
        gll16(asrc1 + k0, &LA[s][4096 + tid * 8]);
        gll16(bsrc0 + k0, &LB[s][tid * 8]);
        gll16(bsrc1 + k0, &LB[s][4096 + tid * 8]);
    };

    const int kge = (lg ^ ((lr >> 1) & 3)) * 8;
    int aoff[8], boff[4];
    #pragma unroll
    for (int m = 0; m < 8; ++m) aoff[m] = (wm * 128 + m * 16 + lr) * 32 + kge;
    #pragma unroll
    for (int n = 0; n < 4; ++n) boff[n] = (wn * 64 + n * 16 + lr) * 32 + kge;

    f32x4 acc[8][4] = {};
    short8 af[8], bf[4];

    const int nk = Keff >> 5;
    STAGE(0, 0);
    STAGE(1, 32);
    asm volatile("s_waitcnt vmcnt(4)" ::: "memory");
    asm volatile("s_barrier" ::: "memory");
    __builtin_amdgcn_sched_barrier(0);

    auto BODY = [&](int t, int s, bool doStage) {
        #pragma unroll
        for (int m = 0; m < 8; ++m) af[m] = *(const short8*)(&LA[s][aoff[m]]);
        #pragma unroll
        for (int n = 0; n < 4; ++n) bf[n] = *(const short8*)(&LB[s][boff[n]]);
        asm volatile("s_waitcnt lgkmcnt(0)" ::: "memory");
        __builtin_amdgcn_sched_barrier(0);
        __builtin_amdgcn_s_setprio(1);
        #pragma unroll
        for (int m = 0; m < 4; ++m)
            #pragma unroll
            for (int n = 0; n < 4; ++n)
                acc[m][n] = mfma16(af[m], bf[n], acc[m][n]);
        __builtin_amdgcn_s_setprio(0);
        asm volatile("s_barrier" ::: "memory");
        __builtin_amdgcn_sched_barrier(0);
        if (doStage) STAGE(s, (t + 2) * 32);
        __builtin_amdgcn_s_setprio(1);
        #pragma unroll
        for (int m = 4; m < 8; ++m)
            #pragma unroll
            for (int n = 0; n < 4; ++n)
                acc[m][n] = mfma16(af[m], bf[n], acc[m][n]);
        __builtin_amdgcn_s_setprio(0);
    };

    for (int t = 0; t < nk - 2; ++t) {
        BODY(t, t & 1, true);
        asm volatile("s_waitcnt vmcnt(4)" ::: "memory");
        __builtin_amdgcn_sched_barrier(0);
        asm volatile("s_barrier" ::: "memory");
        __builtin_amdgcn_sched_barrier(0);
    }
    BODY(nk - 2, (nk - 2) & 1, false);
    asm volatile("s_waitcnt vmcnt(0)" ::: "memory");
    __builtin_amdgcn_sched_barrier(0);
    asm volatile("s_barrier" ::: "memory");
    __builtin_amdgcn_sched_barrier(0);
    BODY(nk - 1, (nk - 1) & 1, false);

    #pragma unroll
    for (int m = 0; m < 8; ++m) {
        const int rb = bm * 256 + wm * 128 + m * 16 + lg * 4;
        #pragma unroll
        for (int n = 0; n < 4; ++n) {
            const int col = bn * 256 + wn * 64 + n * 16 + lr;
            const float bvl = (EPI == EPI_PART) ? 0.f : bias[col];
            #pragma unroll
            for (int j = 0; j < 4; ++j) {
                const int r = rb + j;
                if (r >= M) continue;
                const float v = acc[m][n][j] + bvl;
                const size_t oi = (size_t)r * N + col;
                if (EPI == EPI_QKV) {
                    const int q = col >> 10, lc = col & 1023;
                    u16* dst = (q == 0) ? outB : ((q == 1) ? outB2 : outB3);
                    dst[(size_t)r * 1024 + lc] = f2bf(v);
                }
                else if (EPI == EPI_B_RELU_BF16) outB[oi] = f2bf(fmaxf(v, 0.f));
                else if (EPI == EPI_B_RES_F32)   outF[oi] = v + extra[oi];
                else if (EPI == EPI_EMBED)       outF[oi] = v * 32.0f + extra[(size_t)(r % 300) * 1024 + col];
                else if (EPI == EPI_PART)        outF[(size_t)z * M * N + oi] = v;
            }
        }
    }
}

// ==== 128x128 BK=32 RING-2 counted-vmcnt GEMM, 256 threads / 4 waves 2x2 (proven r13) ====
// Relaxed wait: compiler schedules lgkmcnt for phase-A MFMAs; explicit lgkmcnt(0) only
// before the slot-sealing barrier (all slot-s ds_reads must retire before restage).
template<int EPI>
__global__ void __launch_bounds__(256, 3) gemm_mid(const u16* __restrict__ A, const u16* __restrict__ Bt,
        const float* __restrict__ bias, const float* __restrict__ extra,
        float* outF, u16* outB, u16* outB2, u16* outB3,
        int M, int N, int K, int lda, int ldb)
{
    __shared__ __align__(16) u16 LA[2][128 * 32];   // 8 KB x2
    __shared__ __align__(16) u16 LB[2][128 * 32];   // 8 KB x2  (total 32 KB)
    const int tid = threadIdx.x;
    int lin = blockIdx.x;
    const int nwg = gridDim.x;
    if ((nwg & 7) == 0) { const int cpx = nwg >> 3; lin = (lin & 7) * cpx + (lin >> 3); }
    const int ntN = N >> 7;
    const int bm = lin / ntN, bn = lin - (lin / ntN) * ntN;

    const int lane = tid & 63, wid = tid >> 6;
    const int wr = wid >> 1, wc = wid & 1;          // 2 x 2 waves
    const int lg = lane >> 4, lr = lane & 15;

    const int prow = tid >> 2;
    const int skg  = (((tid & 3) ^ ((tid >> 3) & 3)) * 8);
    const u16* asrc0 = A  + (size_t)imin(bm * 128 + prow,      M - 1) * lda + skg;
    const u16* asrc1 = A  + (size_t)imin(bm * 128 + prow + 64, M - 1) * lda + skg;
    const u16* bsrc0 = Bt + (size_t)(bn * 128 + prow)      * ldb + skg;
    const u16* bsrc1 = Bt + (size_t)(bn * 128 + prow + 64) * ldb + skg;

    auto STAGE = [&](int s, int k0) {               // 4 loads per thread, 16B each
        gll16(asrc0 + k0, &LA[s][tid * 8]);
        gll16(asrc1 + k0, &LA[s][2048 + tid * 8]);
        gll16(bsrc0 + k0, &LB[s][tid * 8]);
        gll16(bsrc1 + k0, &LB[s][2048 + tid * 8]);
    };

    const int kge = (lg ^ ((lr >> 1) & 3)) * 8;
    int aoff[4], boff[4];
    #pragma unroll
    for (int m = 0; m < 4; ++m) aoff[m] = (wr * 64 + m * 16 + lr) * 32 + kge;
    #pragma unroll
    for (int n = 0; n < 4; ++n) boff[n] = (wc * 64 + n * 16 + lr) * 32 + kge;

    f32x4 acc[4][4] = {};
    short8 af[4], bf[4];

    const int nk = K >> 5;
    STAGE(0, 0);
    STAGE(1, 32);
    asm volatile("s_waitcnt vmcnt(4)" ::: "memory");   // tile0's 4 loads landed; tile1's in flight
    asm volatile("s_barrier" ::: "memory");
    __builtin_amdgcn_sched_barrier(0);

    auto BODY = [&](int t, int s, bool doStage) {
        #pragma unroll
        for (int m = 0; m < 4; ++m) af[m] = *(const short8*)(&LA[s][aoff[m]]);
        #pragma unroll
        for (int n = 0; n < 4; ++n) bf[n] = *(const short8*)(&LB[s][boff[n]]);
        // phase A: compiler inserts precise lgkmcnt for af[0..1]/bf deps; af[2..3] may overlap
        __builtin_amdgcn_s_setprio(1);
        #pragma unroll
        for (int m = 0; m < 2; ++m)
            #pragma unroll
            for (int n = 0; n < 4; ++n)
                acc[m][n] = mfma16(af[m], bf[n], acc[m][n]);
        __builtin_amdgcn_s_setprio(0);
        asm volatile("s_waitcnt lgkmcnt(0)" ::: "memory");   // ALL slot-s reads retired
        __builtin_amdgcn_sched_barrier(0);
        asm volatile("s_barrier" ::: "memory");              // seals all waves' reads of slot s
        __builtin_amdgcn_sched_barrier(0);
        if (doStage) STAGE(s, (t + 2) * 32);
        __builtin_amdgcn_s_setprio(1);
        #pragma unroll
        for (int m = 2; m < 4; ++m)
            #pragma unroll
            for (int n = 0; n < 4; ++n)
                acc[m][n] = mfma16(af[m], bf[n], acc[m][n]);
        __builtin_amdgcn_s_setprio(0);
    };

    for (int t = 0; t < nk - 2; ++t) {
        BODY(t, t & 1, true);
        asm volatile("s_waitcnt vmcnt(4)" ::: "memory");     // tile t+1 landed; t+2 stays in flight
        __builtin_amdgcn_sched_barrier(0);
        asm volatile("s_barrier" ::: "memory");
        __builtin_amdgcn_sched_barrier(0);
    }
    BODY(nk - 2, (nk - 2) & 1, false);
    asm volatile("s_waitcnt vmcnt(0)" ::: "memory");
    __builtin_amdgcn_sched_barrier(0);
    asm volatile("s_barrier" ::: "memory");
    __builtin_amdgcn_sched_barrier(0);
    BODY(nk - 1, (nk - 1) & 1, false);

    #pragma unroll
    for (int m = 0; m < 4; ++m) {
        const int rb = bm * 128 + wr * 64 + m * 16 + lg * 4;
        #pragma unroll
        for (int n = 0; n < 4; ++n) {
            const int col = bn * 128 + wc * 64 + n * 16 + lr;
            const float bvl = bias[col];
            #pragma unroll
            for (int j = 0; j < 4; ++j) {
                const int r = rb + j;
                if (r >= M) continue;
                const float v = acc[m][n][j] + bvl;
                const size_t oi = (size_t)r * N + col;
                if      (EPI == EPI_B_RES_F32)   outF[oi] = v + extra[oi];
                else if (EPI == EPI_EMBED)       outF[oi] = v * 32.0f + extra[(size_t)(r % 300) * 1024 + col];
                else if (EPI == EPI_B_RELU_BF16) outB[oi] = f2bf(fmaxf(v, 0.f));
                else if (EPI == EPI_B_TANH_F32)  outF[oi] = tanhf(v);
                else if (EPI == EPI_QKV) {
                    const int q = col >> 10, lc = col & 1023;
                    u16* dst = (q == 0) ? outB : ((q == 1) ? outB2 : outB3);
                    dst[(size_t)r * 1024 + lc] = f2bf(v);
                }
            }
        }
    }
}

// ---------------- split-K reduce + bias (+tanh) ----------------
template<int TANH>
__global__ void __launch_bounds__(256) redk_kernel(const float* __restrict__ part,
        const float* __restrict__ bias, float* outF, u16* outB, int M, int N, int Z)
{
    const int i = blockIdx.x * 256 + threadIdx.x;
    if (i >= M * N) return;
    const int col = i % N;
    float s = 0.f;
    for (int z = 0; z < Z; ++z) s += part[(size_t)z * M * N + i];
    s += bias[col];
    if (TANH) outB[i] = f2bf(tanhf(s));
    else      outF[i] = s;
}

// ------ attention: scores + softmax -> P bf16 (512 thr / 8 waves, LDS-bounce coalesced) ------
__global__ void __launch_bounds__(512) attn_scores_kernel(const u16* __restrict__ Qb,
        const u16* __restrict__ Kb, u16* __restrict__ P)
{
    __shared__ __align__(16) u16 Ks[304 * 128];     // 77824 B, XOR-swizzled rows
    __shared__ __align__(16) u16 Ps[8][16][TP];     // 81920 B per-wave P bounce (tot 159744)
    const int bh = blockIdx.x, b = bh >> 3, h = bh & 7;
    const int tid = threadIdx.x, lane = tid & 63, wid = tid >> 6;
    const int lg = lane >> 4, lr = lane & 15;

    for (int c = tid; c < 304 * 16; c += 512) {
        const int kv = c >> 4, part = c & 15;
        const int tok = b * 300 + imin(kv, 299);
        const short8 v = *(const short8*)(Kb + (size_t)tok * 1024 + h * 128 + part * 8);
        int byte_ = kv * 256 + part * 16;
        byte_ ^= (kv & 7) << 4;
        *(short8*)((char*)Ks + byte_) = v;
    }
    __syncthreads();

    const float scale = 0.08838834764831845f;   // 1/sqrt(128)
    for (int qt = wid; qt < NQT; qt += 8) {
        f32x4 acc[NQT] = {};
        const int qtok = b * 300 + imin(qt * 16 + lr, 299);
        const u16* qrow = Qb + (size_t)qtok * 1024 + h * 128;
        #pragma unroll
        for (int kk = 0; kk < 4; ++kk) {
            const short8 aq = *(const short8*)(qrow + kk * 32 + lg * 8);
            #pragma unroll
            for (int nt = 0; nt < NQT; ++nt) {
                const int kvrow = nt * 16 + lr;
                int byte_ = kvrow * 256 + kk * 64 + lg * 16;
                byte_ ^= (kvrow & 7) << 4;
                const short8 bk = *(const short8*)((char*)Ks + byte_);
                acc[nt] = mfma16(aq, bk, acc[nt]);
            }
        }
        const int sw = lg << 3;     // ((row>>2)&3)<<3 with row = lg*4+j
        #pragma unroll
        for (int j = 0; j < 4; ++j) {
            float vals[NQT];
            float m = -1e30f;
            #pragma unroll
            for (int nt = 0; nt < NQT; ++nt) {
                float s = acc[nt][j] * scale;
                if (nt * 16 + lr >= 300) s = -1e30f;
                vals[nt] = s;
                m = fmaxf(m, s);
            }
            #pragma unroll
            for (int o = 1; o < 16; o <<= 1) m = fmaxf(m, __shfl_xor(m, o));
            float sum = 0.f;
            #pragma unroll
            for (int nt = 0; nt < NQT; ++nt) { const float e = __expf(vals[nt] - m); vals[nt] = e; sum += e; }
            #pragma unroll
            for (int o = 1; o < 16; o <<= 1) sum += __shfl_xor(sum, o);
            const float inv = 1.0f / sum;
            const int row = lg * 4 + j;
            #pragma unroll
            for (int nt = 0; nt < NQT; ++nt) Ps[wid][row][(nt * 16 + lr) ^ sw] = f2bf(vals[nt] * inv);
            Ps[wid][row][(304 + lr) ^ sw] = 0;   // zero kv pad 304..319
        }
        // wave-local flush (NO __syncthreads: waves have unequal qt counts)
        asm volatile("s_waitcnt lgkmcnt(0)" ::: "memory");
        __builtin_amdgcn_sched_barrier(0);
        // coalesced copy-out: 16 rows x 320 u16 = 640 short8
        #pragma unroll
        for (int it = 0; it < 10; ++it) {
            const int idx = it * 64 + lane;
            const int row = idx / 40, c8 = idx - row * 40;
            const int swr = ((row >> 2) & 3) << 3;
            const short8 v8 = *(const short8*)(&Ps[wid][row][(c8 * 8) ^ swr]);
            const int q = qt * 16 + row;
            if (q < 300) *(short8*)(P + ((size_t)bh * 300 + q) * TP + c8 * 8) = v8;
        }
    }
}

// ------ attention: O = P @ V (512 thr / 8 waves, LDS-bounce coalesced) ------
__global__ void __launch_bounds__(512) attn_pv_kernel(const u16* __restrict__ P,
        const u16* __restrict__ Vb, u16* __restrict__ O)
{
    __shared__ __align__(16) u16 Vs[128 * TP];      // 81920 B, V^T XOR-swizzled rows
    __shared__ __align__(16) u16 Os[8][16][128];    // 32768 B per-wave O bounce
    const int bh = blockIdx.x, b = bh >> 3, h = bh & 7;
    const int tid = threadIdx.x, lane = tid & 63, wid = tid >> 6;
    const int lg = lane >> 4, lr = lane & 15;

    for (int c = tid; c < 304 * 16; c += 512) {
        const int kv = c >> 4, dp = c & 15;
        const int tok = b * 300 + imin(kv, 299);
        const short8 v = *(const short8*)(Vb + (size_t)tok * 1024 + h * 128 + dp * 8);
        #pragma unroll
        for (int jj = 0; jj < 8; ++jj) {
            const int d = dp * 8 + jj;
            int byte_ = d * (TP * 2) + kv * 2;
            byte_ ^= (d & 7) << 4;
            *(u16*)((char*)Vs + byte_) = (u16)v[jj];
        }
    }
    for (int c = tid; c < 128 * 16; c += 512) {     // zero kv pad 304..319
        const int d = c >> 4, kv = 304 + (c & 15);
        int byte_ = d * (TP * 2) + kv * 2;
        byte_ ^= (d & 7) << 4;
        *(u16*)((char*)Vs + byte_) = 0;
    }
    __syncthreads();

    for (int qt = wid; qt < NQT; qt += 8) {
        f32x4 acc[8] = {};
        const int q = imin(qt * 16 + lr, 299);
        const u16* prow = P + ((size_t)bh * 300 + q) * TP;
        #pragma unroll
        for (int kk = 0; kk < 10; ++kk) {
            const short8 ap = *(const short8*)(prow + kk * 32 + lg * 8);
            #pragma unroll
            for (int nt = 0; nt < 8; ++nt) {
                const int d = nt * 16 + lr;
                int byte_ = d * (TP * 2) + kk * 64 + lg * 16;
                byte_ ^= (d & 7) << 4;
                const short8 bv8 = *(const short8*)((char*)Vs + byte_);
                acc[nt] = mfma16(ap, bv8, acc[nt]);
            }
        }
        const int sw = lg << 3;
        #pragma unroll
        for (int nt = 0; nt < 8; ++nt)
            #pragma unroll
            for (int j = 0; j < 4; ++j)
                Os[wid][lg * 4 + j][(nt * 16 + lr) ^ sw] = f2bf(acc[nt][j]);
        asm volatile("s_waitcnt lgkmcnt(0)" ::: "memory");
        __builtin_amdgcn_sched_barrier(0);
        #pragma unroll
        for (int it = 0; it < 4; ++it) {
            const int idx = it * 64 + lane;
            const int row = idx >> 4, c8 = idx & 15;
            const int swr = ((row >> 2) & 3) << 3;
            const short8 v8 = *(const short8*)(&Os[wid][row][(c8 * 8) ^ swr]);
            const int qq = qt * 16 + row;
            if (qq < 300)
                *(short8*)(O + ((size_t)(b * 300 + qq)) * 1024 + h * 128 + c8 * 8) = v8;
        }
    }
}

// ---------------- classifier tail ----------------
__global__ void __launch_bounds__(256) logits_kernel(const float* __restrict__ a1,
        const float* __restrict__ cw2, const float* __restrict__ cb2, float* __restrict__ out)
{
    const int tok = blockIdx.x * 4 + (threadIdx.x >> 6);
    const int lane = threadIdx.x & 63;
    if (tok >= NTOK) return;
    const float v0 = a1[(size_t)tok * 128 + lane];
    const float v1 = a1[(size_t)tok * 128 + 64 + lane];
    #pragma unroll
    for (int hp = 0; hp < 4; ++hp) {
        float s = v0 * cw2[lane * 4 + hp] + v1 * cw2[(64 + lane) * 4 + hp];
        #pragma unroll
        for (int o = 1; o < 64; o <<= 1) s += __shfl_xor(s, o);
        if (lane == 0) out[(size_t)tok * 4 + hp] = s + cb2[hp];
    }
}

__global__ void __launch_bounds__(512) softmaxT_kernel(const float* __restrict__ lgt,
        float* __restrict__ alpha, float* __restrict__ outAlpha)
{
    const int bh = blockIdx.x;           // b*4 + hop
    const int b = bh >> 2, hp = bh & 3;
    const int t = threadIdx.x;
    const float v = (t < 300) ? lgt[((size_t)(b * 300 + t)) * 4 + hp] : -1e30f;
    float m = v;
    #pragma unroll
    for (int o = 1; o < 64; o <<= 1) m = fmaxf(m, __shfl_xor(m, o));
    __shared__ float rm[8], rs[8];
    const int lane = t & 63, wid = t >> 6;
    if (lane == 0) rm[wid] = m;
    __syncthreads();
    m = rm[0];
    #pragma unroll
    for (int i = 1; i < 8; ++i) m = fmaxf(m, rm[i]);
    const float e = (t < 300) ? __expf(v - m) : 0.f;
    float s = e;
    #pragma unroll
    for (int o = 1; o < 64; o <<= 1) s += __shfl_xor(s, o);
    if (lane == 0) rs[wid] = s;
    __syncthreads();
    s = rs[0] + rs[1] + rs[2] + rs[3] + rs[4] + rs[5] + rs[6] + rs[7];
    if (t < 300) {
        const float a = e / s;
        alpha[(size_t)bh * 300 + t] = a;
        outAlpha[(size_t)bh * 300 + t] = a;
    }
}

__global__ void __launch_bounds__(256) pool_kernel(const float* __restrict__ alpha,
        const float* __restrict__ xln, float* __restrict__ wsp)
{
    const int bh = blockIdx.x, b = bh >> 2;
    const int d = blockIdx.y * 256 + threadIdx.x;
    const float* xp = xln + (size_t)b * 300 * 1024 + d;
    const float* al = alpha + (size_t)bh * 300;
    float acc = 0.f;
    for (int t = 0; t < 300; ++t) acc += al[t] * xp[(size_t)t * 1024];
    wsp[(size_t)bh * 1024 + d] = acc;
}

// =====================================================================
extern "C" void kernel_launch(void* const* d_in, const int* in_sizes, int n_in,
                              void* d_out, int out_size, void* d_ws, size_t ws_size,
                              hipStream_t stream)
{
    const float* rgb     = (const float*)d_in[0];
    const float* aud     = (const float*)d_in[1];
    const float* embed_W = (const float*)d_in[2];
    const float* embed_b = (const float*)d_in[3];
    const float* Wq      = (const float*)d_in[4];
    const float* bq      = (const float*)d_in[5];
    const float* Wk      = (const float*)d_in[6];
    const float* bk      = (const float*)d_in[7];
    const float* Wv      = (const float*)d_in[8];
    const float* bv      = (const float*)d_in[9];
    const float* Wo      = (const float*)d_in[10];
    const float* bo      = (const float*)d_in[11];
    const float* ln1_a   = (const float*)d_in[12];
    const float* ln1_b   = (const float*)d_in[13];
    const float* W1f     = (const float*)d_in[14];
    const float* b1f     = (const float*)d_in[15];
    const float* W2f     = (const float*)d_in[16];
    const float* b2f     = (const float*)d_in[17];
    const float* ln2_a   = (const float*)d_in[18];
    const float* ln2_b   = (const float*)d_in[19];
    const float* fn_a    = (const float*)d_in[20];
    const float* fn_b    = (const float*)d_in[21];
    const float* cw1     = (const float*)d_in[22];
    const float* cb1     = (const float*)d_in[23];
    const float* cw2     = (const float*)d_in[24];
    const float* cb2     = (const float*)d_in[25];
    const float* cw3     = (const float*)d_in[26];
    const float* cb3     = (const float*)d_in[27];
    const float* cw4     = (const float*)d_in[28];
    const float* cb4     = (const float*)d_in[29];

    const bool bigS = ws_size >= ((size_t)238 << 20);   // host-side constant per process
    const size_t Ssz = bigS ? (size_t)NTOK * DFF * 2 : (size_t)256 * 300 * TP * 2;

    char* base = (char*)d_ws;
    size_t off = 0;
    auto alloc = [&](size_t bytes) -> char* {
        char* p = base + off; off += (bytes + 255) & ~(size_t)255; return p; };

    float* x    = (float*)alloc((size_t)NTOK * DD * 4);        // 39.3 MB (c3T aliases after final LN)
    float* pe   = (float*)alloc((size_t)TT * DD * 4);          //  1.2 MB
    u16*  hbuf  = (u16*) alloc((size_t)NTOK * DD * 2);         // 19.7 MB (Ob aliases)
    u16*  Qb    = (u16*) alloc((size_t)NTOK * DD * 2);         // 19.7 MB (xln aliases Qb+Kb)
    u16*  Kb    = (u16*) alloc((size_t)NTOK * DD * 2);         // 19.7 MB
    u16*  Vb    = (u16*) alloc((size_t)NTOK * DD * 2);         // 19.7 MB (xlnb aliases)
    u16*  S     = (u16*) alloc(Ssz);                           // 49.2 or 78.6 MB shared region
    float* lgts = (float*)alloc((size_t)NTOK * 4 * 4);
    float* alph = (float*)alloc((size_t)128 * 300 * 4);
    float* wsp  = (float*)alloc((size_t)32 * 4096 * 4);
    u16*  wsb   = (u16*) alloc((size_t)32 * 4096 * 2);
    u16*  t3b   = (u16*) alloc((size_t)32 * 4096 * 2);
    float* bqkv = (float*)alloc((size_t)4 * 3072 * 4);         // fused QKV bias
    u16*  eWt   = (u16*) alloc((size_t)1024 * 1152 * 2);       //  2.4 MB
    u16*  WqkvT = (u16*) alloc((size_t)3 * 1024 * 1024 * 2);   //  6.3 MB (fused, per-layer reuse)
    u16*  WoT   = (u16*) alloc((size_t)1024 * 1024 * 2);
    u16*  W1T   = (u16*) alloc((size_t)DFF * DD * 2);          //  8.4 MB [DFF rows, DD]
    u16*  W2T   = (u16*) alloc((size_t)DD * DFF * 2);          //  8.4 MB [DD rows, DFF]
    u16*  c1T   = (u16*) alloc((size_t)128 * 1024 * 2);
    if (off > ws_size) return;   // loud failure if insufficient

    u16*  featsb = S;             // 22.1 MB, dead after embed GEMM
    u16*  pbuf   = S;             // 49.2 MB, attn P for all 256 bh (dead outside attn)
    u16*  midc   = S;             // FFN activation (full DFF if bigS, else half)
    u16*  Ob     = hbuf;          // attention output (hbuf dead after QKV gemm)
    float* xln   = (float*)Qb;    // final-LN f32 output: spans Qb+Kb (both dead)
    u16*  xlnb   = Vb;            // final-LN bf16 output (Vb dead)
    float* a1    = (float*)S;     // 4.9 MB, classifier phase
    u16*  c3T    = (u16*)x;       // 32.0 MB  <= 39.3 (x dead after final LN)
    u16*  c4T    = S;             // 31.6 MB  (written after logits; a1 dead)
    float* part  = (float*)hbuf;  // classifier split-K partials (hbuf dead in classifier)
    float* outv     = (float*)d_out;
    float* outAlpha = outv + (size_t)32 * NCLS;

    const dim3 blk(256);

    pe_kernel<<<(TT * DD + 255) / 256, blk, 0, stream>>>(pe);
    feats_kernel<<<(int)(((size_t)NTOK * FIN + 255) / 256), blk, 0, stream>>>(rgb, aud, featsb);
    qkvbias_kernel<<<(4 * 3072 + 255) / 256, blk, 0, stream>>>(bq, bk, bv, bqkv);

    auto wconv = [&](const float* W, u16* Wt, int K, int N) {
        dim3 g((N + 31) / 32, (K + 31) / 32);
        wconv_kernel<<<g, dim3(32, 8), 0, stream>>>(W, Wt, K, N);
    };
    wconv(embed_W, eWt, FIN, DD);
    wconv(cw1, c1T, DD, DATT);

    // embed: x = (feats @ W + b)*sqrt(D) + PE   (gemm_mid ring-2, grid 600 %8==0)
    gemm_mid<EPI_EMBED><<<600, blk, 0, stream>>>(featsb, eWt, embed_b, pe, x,
            nullptr, nullptr, nullptr, NTOK, DD, FIN, FIN, FIN);

    for (int i = 0; i < 4; ++i) {
        wconv3_kernel<<<dim3(32, 32, 3), dim3(32, 8), 0, stream>>>(
                Wq + (size_t)i * DD * DD, Wk + (size_t)i * DD * DD, Wv + (size_t)i * DD * DD, WqkvT);
        wconv(Wo  + (size_t)i * DD * DD,  WoT, DD, DD);
        wconv(W1f + (size_t)i * DD * DFF, W1T, DD, DFF);
        wconv(W2f + (size_t)i * DFF * DD, W2T, DFF, DD);

        ln_kernel<0><<<NTOK, blk, 0, stream>>>(x, ln1_a + (size_t)i * DD, ln1_b + (size_t)i * DD, hbuf, nullptr);
        // fused QKV: gemm_mid ring-2, grid 75*24 = 1800 (%8==0)
        gemm_mid<EPI_QKV><<<1800, blk, 0, stream>>>(hbuf, WqkvT, bqkv + (size_t)i * 3072, nullptr,
                nullptr, Qb, Kb, Vb, NTOK, 3072, DD, DD, DD);
        attn_scores_kernel<<<256, dim3(512), 0, stream>>>(Qb, Kb, pbuf);
        attn_pv_kernel<<<256, dim3(512), 0, stream>>>(pbuf, Vb, Ob);   // Ob = hbuf (dead now)
        // Wo + residual: gemm_mid ring-2, grid 600
        gemm_mid<EPI_B_RES_F32><<<600, blk, 0, stream>>>(Ob, WoT, bo + (size_t)i * DD, x, x,
                nullptr, nullptr, nullptr, NTOK, DD, DD, DD, DD);
        ln_kernel<0><<<NTOK, blk, 0, stream>>>(x, ln2_a + (size_t)i * DD, ln2_b + (size_t)i * DD, hbuf, nullptr);
        if (bigS) {
            // FFN1: gemm_mid ring-2, grid 75*32 = 2400 (%8==0); FFN2: gemm_mid, grid 600, K=4096
            gemm_mid<EPI_B_RELU_BF16><<<2400, blk, 0, stream>>>(hbuf, W1T, b1f + (size_t)i * DFF,
                    nullptr, nullptr, midc, nullptr, nullptr, NTOK, DFF, DD, DD, DD);
            gemm_mid<EPI_B_RES_F32><<<600, blk, 0, stream>>>(midc, W2T, b2f + (size_t)i * DD, x, x,
                    nullptr, nullptr, nullptr, NTOK, DD, DFF, DFF, DFF);
        } else {
            for (int h = 0; h < 2; ++h) {
                gemm_big<EPI_B_RELU_BF16><<<304, dim3(512), 0, stream>>>(hbuf, W1T + (size_t)h * 2048 * DD,
                        b1f + (size_t)i * DFF + h * 2048, nullptr, nullptr, midc, nullptr, nullptr,
                        NTOK, 2048, DD, DD, DD, 0);
                if (h == 0)
                    gemm_k<EPI_B_RES_F32, 1><<<dim3(8, 75), blk, 0, stream>>>(midc, W2T + (size_t)h * 2048,
                            b2f + (size_t)i * DD, x, x, nullptr, nullptr, nullptr, NTOK, DD, 2048, 2048, DFF, 0);
                else
                    gemm_k<EPI_ACC_F32, 1><<<dim3(8, 75), blk, 0, stream>>>(midc, W2T + (size_t)h * 2048,
                            b2f + (size_t)i * DD, x, x, nullptr, nullptr, nullptr, NTOK, DD, 2048, 2048, DFF, 0);
            }
        }
    }

    ln_kernel<1><<<NTOK, blk, 0, stream>>>(x, fn_a, fn_b, xlnb, xln);
    wconv(cw3, c3T, 4096, DFF);                               // x dead -> c3T
    // a1 = tanh(xlnb @ c1T + cb1): gemm_mid, grid 75 (no swizzle, fine)
    gemm_mid<EPI_B_TANH_F32><<<75, blk, 0, stream>>>(xlnb, c1T, cb1, nullptr, a1,
            nullptr, nullptr, nullptr, NTOK, DATT, DD, DD, DD);
    logits_kernel<<<2400, blk, 0, stream>>>(a1, cw2, cb2, lgts);
    wconv(cw4, c4T, DFF, NCLS);                               // a1 dead -> c4T
    softmaxT_kernel<<<128, dim3(512), 0, stream>>>(lgts, alph, outAlpha);
    pool_kernel<<<dim3(128, 4), blk, 0, stream>>>(alph, xln, wsp);
    f2bf_kernel<<<(32 * 4096 + 255) / 256, blk, 0, stream>>>(wsp, wsb, 32 * 4096);

    // classifier GEMMs: split-K (Z=8, Kc=512), deterministic reduce
    gemm_k<EPI_PART, 0><<<dim3(32, 1, 8), blk, 0, stream>>>(wsb, c3T, nullptr, nullptr, part,
            nullptr, nullptr, nullptr, 32, 4096, 4096, 4096, 4096, 512);
    redk_kernel<1><<<(32 * 4096 + 255) / 256, blk, 0, stream>>>(part, cb3, nullptr, t3b, 32, 4096, 8);
    gemm_k<EPI_PART, 0><<<dim3(31, 1, 8), blk, 0, stream>>>(t3b, c4T, nullptr, nullptr, part,
            nullptr, nullptr, nullptr, 32, NCLS, 4096, 4096, 4096, 512);
    redk_kernel<0><<<(32 * NCLS + 255) / 256, blk, 0, stream>>>(part, cb4, outv, nullptr, 32, NCLS, 8);
}